// Round 9
// baseline (519.136 us; speedup 1.0000x reference)
//
#include <hip/hip_runtime.h>

#define TS 1000

__device__ __forceinline__ float rl(float v, int l) {
    return __int_as_float(__builtin_amdgcn_readlane(__float_as_int(v), l));
}
__device__ __forceinline__ float fsig(float x) {
    return __builtin_amdgcn_rcpf(1.0f + __expf(-x));
}
__device__ __forceinline__ float ftanh(float x) {
    return 1.0f - 2.0f * __builtin_amdgcn_rcpf(1.0f + __expf(2.0f * x));
}

// One block per (g,b) chain, 8 waves (2/SIMD):
//   wid 0-3 = consumers: U·h(t) partials, K-split 16.
//   wid 4-7 = producers: W·x(t+2) partials, K-split 16, x prefetched deep
//             via inline-asm global_load + tied s_waitcnt vmcnt(2).
// Key schedule fact: ppart[t&3] (gx(t) K-partials) is stable from
// barrier(t-2), so CONSUMERS pre-read + pre-reduce gx(t) BEFORE barrier(t),
// overlapped under their own fma chains. Post-barrier serial path is only
// 4 cpart reads + 12 adds + gates + h.
// One NON-draining s_barrier per step; x loads stay in flight across it.
// Ring audit (all slots: write pre-barrier, read post-barrier-ordered,
// >= 2 barriers between last read and rewrite):
//   cpart[t&1]: write pre-b(t), read post-b(t), rewrite pre-b(t+2).
//   ppart[s=t&3]: write pre-b(t-2), consumer-read pre-b(t) (i.e. post-b(t-1)),
//                 rewrite pre-b(t+2).
// All 4 consumer waves compute gates redundantly with identical slot-order
// sums -> bitwise-identical h replicas -> deterministic across replays.
__global__ __launch_bounds__(512)
__attribute__((amdgpu_waves_per_eu(2, 2)))
void gru_fused8(const float* __restrict__ x, const float* __restrict__ h0,
                const float* __restrict__ W, const float* __restrict__ U,
                const float* __restrict__ bi, const float* __restrict__ bh,
                float* __restrict__ out, float* __restrict__ hout)
{
    __shared__ float4 cpart[2][4][64];   // consumer partials, slot = t & 1
    __shared__ float4 ppart[4][4][64];   // producer partials, slot s holds gx(t), s = t & 3

    const int tid  = threadIdx.x;
    const int lane = tid & 63;
    const int wid  = tid >> 6;
    const int role = wid >> 2;               // 0 = consumer, 1 = producer
    const int sw   = wid & 3;                // K-split index within role
    const int kb   = __builtin_amdgcn_readfirstlane(sw * 16);

    const int g = blockIdx.x >> 5, b = blockIdx.x & 31;

    // 48 stationary weights/lane: k-rows kb..kb+15, 3 gate columns.
    float w0[16], w1[16], w2[16];
    {
        const float* P = ((role == 0) ? U : W) + (size_t)g * (64 * 192) + (size_t)kb * 192 + lane;
        #pragma unroll
        for (int k = 0; k < 16; ++k) {
            w0[k] = P[k * 192];
            w1[k] = P[k * 192 + 64];
            w2[k] = P[k * 192 + 128];
        }
    }
    #pragma unroll
    for (int k = 0; k < 16; ++k)
        asm volatile("" : "+v"(w0[k]), "+v"(w1[k]), "+v"(w2[k]));

    // b_h folded into consumer sw0; b_i folded into producer sw0.
    float bz = 0.f, br = 0.f, bn = 0.f;
    if (sw == 0) {
        const float* bb = ((role == 0) ? bh : bi) + g * 192 + lane;
        bz = bb[0]; br = bb[64]; bn = bb[128];
    }

    float h = 0.f;
    if (role == 0) h = h0[(g * 32 + b) * 64 + lane];   // replicated, 4 consumer waves

    const float* xp = x + (size_t)b * (TS * 512) + g * 64 + lane;
    float* op = out + (size_t)b * (TS * 512) + g * 64 + lane;

    // Producer x register sets, written ONLY by asm loads, statically indexed
    // via the 4x-unrolled t-loop: set (time & 3) holds x(time).
    float xs0 = 0.f, xs1 = 0.f, xs2 = 0.f, xs3 = 0.f;

#define XLOAD(DST, T_)                                                        \
    { const float* pp_ = xp + (size_t)(T_) * 512;                             \
      asm volatile("global_load_dword %0, %1, off" : "=v"(DST) : "v"(pp_)); }

#define PPROD(XS, SLOT)                                                       \
    {                                                                         \
        float az = bz, ar = br, an = bn;                                      \
        float az2 = 0.f, ar2 = 0.f, an2 = 0.f;                                \
        _Pragma("unroll")                                                     \
        for (int k = 0; k < 8; ++k) {                                         \
            const float s = rl(XS, kb + k);                                   \
            az = fmaf(s, w0[k], az);                                          \
            ar = fmaf(s, w1[k], ar);                                          \
            an = fmaf(s, w2[k], an);                                          \
        }                                                                     \
        _Pragma("unroll")                                                     \
        for (int k = 8; k < 16; ++k) {                                        \
            const float s = rl(XS, kb + k);                                   \
            az2 = fmaf(s, w0[k], az2);                                        \
            ar2 = fmaf(s, w1[k], ar2);                                        \
            an2 = fmaf(s, w2[k], an2);                                        \
        }                                                                     \
        ppart[SLOT][sw][lane] = make_float4(az + az2, ar + ar2, an + an2, 0.f); \
    }

    // ---- producer prologue: gx(0)->ppart[0], gx(1)->ppart[1]; x(2),x(3) in flight.
    if (role == 1) {
        XLOAD(xs0, 0) XLOAD(xs1, 1) XLOAD(xs2, 2) XLOAD(xs3, 3)
        asm volatile("s_waitcnt vmcnt(2)" : "+v"(xs0), "+v"(xs1));
        PPROD(xs0, 0)
        PPROD(xs1, 1)
    }
    asm volatile("s_waitcnt lgkmcnt(0)" ::: "memory");
    __builtin_amdgcn_s_barrier();

#define BODY(J, XS_USE, XS_FILL)                                              \
    {                                                                         \
        const int t = tt + (J);                                               \
        float gxz, gxr, gxn;                                                  \
        float caz, car, can;                                                  \
        if (role == 0) {                                                      \
            /* pre-read gx(t): stable since barrier(t-2) */                   \
            const float4 q0 = ppart[(J) & 3][0][lane];                        \
            const float4 q1 = ppart[(J) & 3][1][lane];                        \
            const float4 q2 = ppart[(J) & 3][2][lane];                        \
            const float4 q3 = ppart[(J) & 3][3][lane];                        \
            float az = bz, ar = br, an = bn;                                  \
            float az2 = 0.f, ar2 = 0.f, an2 = 0.f;                            \
            _Pragma("unroll")                                                 \
            for (int k = 0; k < 8; ++k) {                                     \
                const float s = rl(h, kb + k);                                \
                az = fmaf(s, w0[k], az);                                      \
                ar = fmaf(s, w1[k], ar);                                      \
                an = fmaf(s, w2[k], an);                                      \
            }                                                                 \
            _Pragma("unroll")                                                 \
            for (int k = 8; k < 16; ++k) {                                    \
                const float s = rl(h, kb + k);                                \
                az2 = fmaf(s, w0[k], az2);                                    \
                ar2 = fmaf(s, w1[k], ar2);                                    \
                an2 = fmaf(s, w2[k], an2);                                    \
            }                                                                 \
            caz = az + az2; car = ar + ar2; can = an + an2;                   \
            cpart[(J) & 1][sw][lane] = make_float4(caz, car, can, 0.f);       \
            gxz = ((q0.x + q1.x) + q2.x) + q3.x;                              \
            gxr = ((q0.y + q1.y) + q2.y) + q3.y;                              \
            gxn = ((q0.z + q1.z) + q2.z) + q3.z;                              \
        } else {                                                              \
            /* issue x(t+4) into the set freed 2 bodies ago */                \
            int tl = t + 4; if (tl > TS - 1) tl = TS - 1;                     \
            XLOAD(XS_FILL, tl)                                                \
            /* x(t+2) guaranteed arrived: 3 outstanding -> wait to 2 */       \
            asm volatile("s_waitcnt vmcnt(2)" : "+v"(XS_USE));                \
            PPROD(XS_USE, (J + 2) & 3)                                        \
        }                                                                     \
        asm volatile("s_waitcnt lgkmcnt(0)" ::: "memory");                    \
        __builtin_amdgcn_sched_barrier(0);                                    \
        __builtin_amdgcn_s_barrier();          /* NO vmcnt drain */           \
        __builtin_amdgcn_sched_barrier(0);                                    \
        if (role == 0) {                                                      \
            __builtin_amdgcn_s_setprio(1);     /* consumer = critical path */ \
            const float4 c0 = cpart[(J) & 1][0][lane];                        \
            const float4 c1 = cpart[(J) & 1][1][lane];                        \
            const float4 c2 = cpart[(J) & 1][2][lane];                        \
            const float4 c3 = cpart[(J) & 1][3][lane];                        \
            const float ghz = ((c0.x + c1.x) + c2.x) + c3.x;                  \
            const float ghr = ((c0.y + c1.y) + c2.y) + c3.y;                  \
            const float ghn = ((c0.z + c1.z) + c2.z) + c3.z;                  \
            const float z = fsig(gxz + ghz);                                  \
            const float r = fsig(gxr + ghr);                                  \
            const float n = ftanh(fmaf(r, ghn, gxn));   /* reset_after */     \
            h = n + z * (h - n);                                              \
            __builtin_amdgcn_s_setprio(0);                                    \
            if (sw == 0) op[(size_t)t * 512] = h;                             \
        }                                                                     \
    }

    for (int tt = 0; tt < TS; tt += 4) {
        BODY(0, xs2, xs0)
        BODY(1, xs3, xs1)
        BODY(2, xs0, xs2)
        BODY(3, xs1, xs3)
    }
#undef BODY
#undef PPROD
#undef XLOAD

    if (role == 0 && sw == 0)
        hout[(g * 32 + b) * 64 + lane] = h;
}

extern "C" void kernel_launch(void* const* d_in, const int* in_sizes, int n_in,
                              void* d_out, int out_size, void* d_ws, size_t ws_size,
                              hipStream_t stream) {
    const float* x  = (const float*)d_in[0];
    const float* h0 = (const float*)d_in[1];
    const float* W  = (const float*)d_in[2];
    const float* U  = (const float*)d_in[3];
    const float* bi = (const float*)d_in[4];
    const float* bh = (const float*)d_in[5];
    float* out  = (float*)d_out;
    float* hout = out + (size_t)32 * TS * 512;
    hipLaunchKernelGGL(gru_fused8, dim3(256), dim3(512), 0, stream,
                       x, h0, W, U, bi, bh, out, hout);
}